// Round 1
// baseline (1764.482 us; speedup 1.0000x reference)
//
#include <hip/hip_runtime.h>

// ---------------------------------------------------------------- constants
constexpr int NC  = 16;    // n_chunks
constexpr int LL  = 1024;  // chunk len
constexpr int DM  = 512;   // d_model
constexpr int DI  = 1024;  // d_inner
constexpr int DS  = 16;    // d_state
constexpr int DTR = 32;    // dt_rank
constexpr int NH  = 8;     // heads
constexpr int DH  = 64;    // head dim
constexpr int NTOK = NC * LL;  // 16384

__device__ __forceinline__ float softplusf(float x) {
    return x > 20.f ? x : log1pf(__expf(x));
}
__device__ __forceinline__ float siluf(float x) {
    return x / (1.f + __expf(-x));
}

// ---------------------------------------------------------------- SGEMM
// C[M,N] = act(A[M,K]*B[K,N] + bias) (+ Cin).  Row-major, all dims divide tiles.
// BM*BK == 1024 and BN*BK == 1024 (one float4 per thread per tile for A and B).
template<int BM, int BN, int BK, int TM, int TN, int ACT, bool BIAS, bool ADDC>
__global__ __launch_bounds__(256)
void sgemm(const float* __restrict__ A, int lda,
           const float* __restrict__ B, int ldb,
           const float* __restrict__ bias,
           const float* __restrict__ Cin, int ldcin,
           float* __restrict__ C, int ldc,
           int K)
{
    __shared__ float As[BK][BM];
    __shared__ float Bs[BK][BN];
    const int tid = threadIdx.x;
    const int bm = blockIdx.y * BM;
    const int bn = blockIdx.x * BN;

    const int AR = tid / (BK / 4);
    const int AC = (tid % (BK / 4)) * 4;
    const int BR = tid / (BN / 4);
    const int BC = (tid % (BN / 4)) * 4;
    const int tx = tid % (BN / TN);
    const int ty = tid / (BN / TN);

    float acc[TM][TN] = {};

    for (int k0 = 0; k0 < K; k0 += BK) {
        float4 av = *(const float4*)&A[(bm + AR) * lda + k0 + AC];
        float4 bv = *(const float4*)&B[(k0 + BR) * ldb + bn + BC];
        __syncthreads();
        As[AC + 0][AR] = av.x;
        As[AC + 1][AR] = av.y;
        As[AC + 2][AR] = av.z;
        As[AC + 3][AR] = av.w;
        *(float4*)&Bs[BR][BC] = bv;
        __syncthreads();
#pragma unroll
        for (int kk = 0; kk < BK; ++kk) {
            float a[TM], b[TN];
#pragma unroll
            for (int i = 0; i < TM; i += 4)
                *(float4*)&a[i] = *(const float4*)&As[kk][ty * TM + i];
#pragma unroll
            for (int j = 0; j < TN; j += 4)
                *(float4*)&b[j] = *(const float4*)&Bs[kk][tx * TN + j];
#pragma unroll
            for (int i = 0; i < TM; ++i)
#pragma unroll
                for (int j = 0; j < TN; ++j)
                    acc[i][j] = fmaf(a[i], b[j], acc[i][j]);
        }
    }

#pragma unroll
    for (int i = 0; i < TM; ++i) {
        int row = bm + ty * TM + i;
#pragma unroll
        for (int j = 0; j < TN; ++j) {
            int col = bn + tx * TN + j;
            float v = acc[i][j];
            if (BIAS) v += bias[col];
            if (ACT == 1) v = softplusf(v);
            if (ADDC) v += Cin[row * ldcin + col];
            C[row * ldc + col] = v;
        }
    }
}

// ---------------------------------------------------------------- conv + silu
__global__ __launch_bounds__(256)
void conv_kernel(const float* __restrict__ xi, const float* __restrict__ conv_w,
                 const float* __restrict__ conv_b, float* __restrict__ xc)
{
    int idx = blockIdx.x * 256 + threadIdx.x;      // [NTOK*DI)
    int d = idx & (DI - 1);
    int ct = idx >> 10;
    int t = ct & (LL - 1);
    float4 w = *(const float4*)&conv_w[d * 4];
    float acc = conv_b[d];
    if (t >= 3) acc = fmaf(xi[(ct - 3) * DI + d], w.x, acc);
    if (t >= 2) acc = fmaf(xi[(ct - 2) * DI + d], w.y, acc);
    if (t >= 1) acc = fmaf(xi[(ct - 1) * DI + d], w.z, acc);
    acc = fmaf(xi[ct * DI + d], w.w, acc);
    xc[idx] = siluf(acc);
}

// ---------------------------------------------------------------- selective scan
// one thread per (chunk, d_inner) chain; h[DS] in registers.
// reads dt from dty, writes y into dty in-place (same element, same thread).
__global__ __launch_bounds__(64)
void scan_kernel(float* dty,
                 const float* __restrict__ xcp,
                 const float* __restrict__ zp,
                 const float* __restrict__ dbc,
                 const float* __restrict__ A_log,
                 const float* __restrict__ Dp)
{
    const int c = blockIdx.x >> 4;                 // 16 blocks per chunk
    const int d = ((blockIdx.x & 15) << 6) + threadIdx.x;
    const int tid = threadIdx.x;

    float Areg[DS];
#pragma unroll
    for (int s = 0; s < DS; ++s) Areg[s] = -__expf(A_log[d * DS + s]);
    float h[DS] = {};
    const float Dpd = Dp[d];

    __shared__ float sBC[2][32];
    if (tid < 32) sBC[0][tid] = dbc[(c * LL) * 64 + 32 + tid];
    __syncthreads();

    int idx = c * LL * DI + d;
    float cdt = dty[idx], cxc = xcp[idx], cz = zp[idx];

    for (int t = 0; t < LL; ++t) {
        const int cur = t & 1;
        float preBC = 0.f, ndt = 0.f, nxc = 0.f, nz = 0.f;
        const bool more = (t + 1 < LL);
        if (more) {
            if (tid < 32) preBC = dbc[(c * LL + t + 1) * 64 + 32 + tid];
            ndt = dty[idx + DI];
            nxc = xcp[idx + DI];
            nz  = zp[idx + DI];
        }
        float dtx = cdt * cxc;
        float yt = 0.f;
#pragma unroll
        for (int s = 0; s < DS; ++s) {
            float dA = __expf(cdt * Areg[s]);
            h[s] = fmaf(dA, h[s], dtx * sBC[cur][s]);
            yt = fmaf(h[s], sBC[cur][16 + s], yt);
        }
        dty[idx] = (yt + cxc * Dpd) * siluf(cz);
        if (more && tid < 32) sBC[cur ^ 1][tid] = preBC;
        __syncthreads();
        cdt = ndt; cxc = nxc; cz = nz;
        idx += DI;
    }
}

// ---------------------------------------------------------------- mean over L
__global__ __launch_bounds__(64)
void mean_kernel(const float* __restrict__ chunks, float* __restrict__ meanb)
{
    int j = blockIdx.x * 64 + threadIdx.x;
    int c = blockIdx.y;
    float s = 0.f;
    for (int t = 0; t < LL; ++t) s += chunks[(c * LL + t) * DM + j];
    meanb[c * DM + j] = s * (1.f / LL);
}

// ---------------------------------------------------------------- summaries
__global__ __launch_bounds__(256)
void summ_kernel(const float* __restrict__ meanb, const float* __restrict__ sum_w,
                 const float* __restrict__ sum_b, float* __restrict__ summ)
{
    int n = blockIdx.x * 256 + threadIdx.x;
    int c = blockIdx.y;
    float acc = sum_b[n];
    for (int k = 0; k < DM; ++k) acc = fmaf(meanb[c * DM + k], sum_w[k * DM + n], acc);
    summ[c * DM + n] = acc;
}

__global__ __launch_bounds__(256)
void kv_kernel(const float* __restrict__ summ, const float* __restrict__ wk,
               const float* __restrict__ wv, float* __restrict__ kb,
               float* __restrict__ vb)
{
    int n = blockIdx.x * 256 + threadIdx.x;
    int c = blockIdx.y;
    float ak = 0.f, av = 0.f;
    for (int k = 0; k < DM; ++k) {
        float s = summ[c * DM + k];
        ak = fmaf(s, wk[k * DM + n], ak);
        av = fmaf(s, wv[k * DM + n], av);
    }
    kb[c * DM + n] = ak;
    vb[c * DM + n] = av;
}

// ---------------------------------------------------------------- cross-attn
// block per token; scores+softmax in-block; attnv overwrites q row in-place.
__global__ __launch_bounds__(128)
void attn_kernel(float* qv,                      // [NTOK, DM] q in / attnv out
                 const float* __restrict__ kb,   // [NC, DM]
                 const float* __restrict__ vb)   // [NC, DM]
{
    __shared__ float sq[DM];
    __shared__ float sAttn[NH][NC];
    const int ct = blockIdx.x;
    const int c = ct >> 10;
    const int tid = threadIdx.x;

    *(float4*)&sq[tid * 4] = *(const float4*)&qv[ct * DM + tid * 4];
    __syncthreads();

    const int h = tid >> 4, j = tid & 15;
    const float* kr = kb + j * DM + h * DH;
    const float* qr = sq + h * DH;
    float s = 0.f;
#pragma unroll
    for (int d0 = 0; d0 < DH; d0 += 4) {
        float4 k4 = *(const float4*)&kr[d0];
        float4 q4 = *(const float4*)&qr[d0];
        s += q4.x * k4.x + q4.y * k4.y + q4.z * k4.z + q4.w * k4.w;
    }
    s *= 0.125f;                                  // 1/sqrt(64)
    if (j == c) s = -__builtin_inff();

    float m = s;
#pragma unroll
    for (int o = 1; o < 16; o <<= 1) m = fmaxf(m, __shfl_xor(m, o));
    float e = __expf(s - m);
    float sum = e;
#pragma unroll
    for (int o = 1; o < 16; o <<= 1) sum += __shfl_xor(sum, o);
    sAttn[h][j] = e / sum;
    __syncthreads();

#pragma unroll
    for (int r = 0; r < 4; ++r) {
        int o = r * 128 + tid;
        int h2 = o >> 6;
        float acc = 0.f;
#pragma unroll
        for (int jj = 0; jj < NC; ++jj)
            acc = fmaf(sAttn[h2][jj], vb[jj * DM + o], acc);
        qv[ct * DM + o] = acc;
    }
}

// ---------------------------------------------------------------- launch
extern "C" void kernel_launch(void* const* d_in, const int* in_sizes, int n_in,
                              void* d_out, int out_size, void* d_ws, size_t ws_size,
                              hipStream_t stream)
{
    const float* chunks   = (const float*)d_in[0];   // [16,1024,512]
    const float* in_proj  = (const float*)d_in[1];   // [512,2048]
    const float* conv_w   = (const float*)d_in[2];   // [1024,4]
    const float* conv_b   = (const float*)d_in[3];   // [1024]
    const float* x_proj   = (const float*)d_in[4];   // [1024,64]
    const float* dt_w     = (const float*)d_in[5];   // [32,1024]
    const float* dt_b     = (const float*)d_in[6];   // [1024]
    const float* A_log    = (const float*)d_in[7];   // [1024,16]
    const float* Dp       = (const float*)d_in[8];   // [1024]
    const float* out_proj = (const float*)d_in[9];   // [1024,512]
    const float* sum_w    = (const float*)d_in[10];  // [512,512]
    const float* sum_b    = (const float*)d_in[11];  // [512]
    const float* wq       = (const float*)d_in[12];  // [512,512]
    const float* wk       = (const float*)d_in[13];  // [512,512]
    const float* wv       = (const float*)d_in[14];  // [512,512]
    const float* wo       = (const float*)d_in[15];  // [512,512]
    float* out = (float*)d_out;

    // workspace layout (floats) — ~206 MB total
    float* ws   = (float*)d_ws;
    float* bufA = ws;                    // [NTOK,DI]  xi -> dt -> y
    float* bufB = bufA + NTOK * DI;      // [NTOK,DI]  z  -> q(512) -> attnv
    float* bufC = bufB + NTOK * DI;      // [NTOK,DI]  xc -> tok(512)
    float* dbc  = bufC + NTOK * DI;      // [NTOK,64]
    float* meanb= dbc + NTOK * 64;       // [16,512]
    float* summ = meanb + NC * DM;       // [16,512]
    float* kb   = summ + NC * DM;        // [16,512]
    float* vb   = kb + NC * DM;          // [16,512]

    dim3 blk256(256), blk128(128), blk64(64);

    // G1a: xi = chunks @ in_proj[:, :1024]
    sgemm<128, 128, 8, 8, 8, 0, false, false><<<dim3(DI / 128, NTOK / 128), blk256, 0, stream>>>(
        chunks, DM, in_proj, 2 * DI, nullptr, nullptr, 0, bufA, DI, DM);
    // G1b: z = chunks @ in_proj[:, 1024:]
    sgemm<128, 128, 8, 8, 8, 0, false, false><<<dim3(DI / 128, NTOK / 128), blk256, 0, stream>>>(
        chunks, DM, in_proj + DI, 2 * DI, nullptr, nullptr, 0, bufB, DI, DM);
    // conv + silu: xc
    conv_kernel<<<NTOK * DI / 256, blk256, 0, stream>>>(bufA, conv_w, conv_b, bufC);
    // G2: dbc = xc @ x_proj   (N=64)
    sgemm<64, 64, 16, 4, 4, 0, false, false><<<dim3(1, NTOK / 64), blk256, 0, stream>>>(
        bufC, DI, x_proj, 64, nullptr, nullptr, 0, dbc, 64, DI);
    // G3: dt = softplus(dbc[:, :32] @ dt_w + dt_b)  -> bufA (xi dead)
    sgemm<128, 128, 8, 8, 8, 1, true, false><<<dim3(DI / 128, NTOK / 128), blk256, 0, stream>>>(
        dbc, 64, dt_w, DI, dt_b, nullptr, 0, bufA, DI, DTR);
    // scan: y -> bufA in-place
    scan_kernel<<<NC * 16, blk64, 0, stream>>>(bufA, bufC, bufB, dbc, A_log, Dp);
    // G4: tok = y @ out_proj -> bufC (xc dead)
    sgemm<128, 128, 8, 8, 8, 0, false, false><<<dim3(DM / 128, NTOK / 128), blk256, 0, stream>>>(
        bufA, DI, out_proj, DM, nullptr, nullptr, 0, bufC, DM, DI);
    // summaries
    mean_kernel<<<dim3(DM / 64, NC), blk64, 0, stream>>>(chunks, meanb);
    summ_kernel<<<dim3(2, NC), blk256, 0, stream>>>(meanb, sum_w, sum_b, summ);
    kv_kernel<<<dim3(2, NC), blk256, 0, stream>>>(summ, wk, wv, kb, vb);
    // G5: q = tok @ wq -> bufB (z dead)
    sgemm<128, 128, 8, 8, 8, 0, false, false><<<dim3(DM / 128, NTOK / 128), blk256, 0, stream>>>(
        bufC, DM, wq, DM, nullptr, nullptr, 0, bufB, DM, DM);
    // attn: scores+softmax+attnv (in-place on bufB rows)
    attn_kernel<<<NTOK, blk128, 0, stream>>>(bufB, kb, vb);
    // G6: out = tok + attnv @ wo
    sgemm<128, 128, 8, 8, 8, 0, false, true><<<dim3(DM / 128, NTOK / 128), blk256, 0, stream>>>(
        bufB, DM, wo, DM, nullptr, bufC, DM, out, DM, DM);
}